// Round 1
// baseline (31.660 us; speedup 1.0000x reference)
//
#include <hip/hip_runtime.h>

#define BB 32
#define CC 384
#define TP 512
#define TF 2048

typedef float f32x4 __attribute__((ext_vector_type(4)));

__device__ __forceinline__ int imax(int a, int b) { return a > b ? a : b; }
__device__ __forceinline__ int imin(int a, int b) { return a < b ? a : b; }

// One kernel, no inter-block dependencies. Grid (32, BB), 256 threads.
//  j<24 : stream 16 c-rows of out (in-block scan -> LDS po16; LDS x gather; nt stores)
//         - xs staged LINEARLY (conflict-free LDS writes), pre-multiplied by phone_mask
//         - frames mapped stride-64 to lanes so each gather instruction reads phones of
//           64 CONSECUTIVE frames (<=2-way bank aliasing = free) instead of stride-4
//           (~5-way). Stores are dword (256B coalesced segments per instruction).
//  j>=24: phone-space GEMV (y kept in LDS) + ldp + frame preds for this
//         block's contiguous frame window; block 31 also writes the tail.
__global__ __launch_bounds__(256, 4) void mono_kernel(
    const float* __restrict__ x, const float* __restrict__ phone_mask,
    const float* __restrict__ frame_mask, const int* __restrict__ duration,
    const float* __restrict__ log_cf0, const float* __restrict__ energy,
    const float* __restrict__ dur_w, const float* __restrict__ dur_b,
    const float* __restrict__ pitch_w, const float* __restrict__ pitch_b,
    const float* __restrict__ pemb_w, const float* __restrict__ pemb_b,
    const float* __restrict__ enp_w, const float* __restrict__ enp_b,
    const float* __restrict__ eemb_w, const float* __restrict__ eemb_b,
    float* __restrict__ out, float* __restrict__ ldp, float* __restrict__ lcp,
    float* __restrict__ vup, float* __restrict__ epp) {
    int b = blockIdx.y;
    int j = blockIdx.x;
    int tid = threadIdx.x;
    int lane = tid & 63;
    int wv = tid >> 6;  // 0..3
    const float* xb = x + (size_t)b * CC * TP;

    if (j < 24) {
        // ---------------- stream block ----------------
        __shared__ short po16[TF];    // 4 KB frame->phone
        __shared__ int ps[256];       // 1 KB pair-scan
        __shared__ float xs[16 * TP]; // 32 KB staged (x * phone_mask) rows
        int c0 = __builtin_amdgcn_readfirstlane(j * 16);
        const float* src = xb + (size_t)c0 * TP;
        const float* pmb = phone_mask + (size_t)b * TP;
        // linear staging: offset q*1024 + tid*4 -> bank = tid*4 % 32 (conflict-free),
        // 1KB contiguous per wave-instruction from global (coalesced).
#pragma unroll
        for (int q = 0; q < 8; ++q) {
            int off = q * 1024 + tid * 4;
            float4 v = *(const float4*)(src + off);
            float4 m = *(const float4*)(pmb + (off & (TP - 1)));
            v.x *= m.x; v.y *= m.y; v.z *= m.z; v.w *= m.w;
            *(float4*)(xs + off) = v;
        }

        int2 d01 = *(const int2*)(duration + b * TP + 2 * tid);
        int d0 = d01.x, d1 = d01.y;
        ps[tid] = d0 + d1;
#pragma unroll
        for (int h = 0; h < 4; ++h) ((int*)po16)[tid + 256 * h] = -1;  // two -1 shorts
        __syncthreads();
        for (int off = 1; off < 256; off <<= 1) {
            int v = (tid >= off) ? ps[tid - off] : 0;
            __syncthreads();
            ps[tid] += v;
            __syncthreads();
        }
        int excl = tid ? ps[tid - 1] : 0;
        int e0 = imin(excl + d0, TF);
        int e1 = imin(excl + d0 + d1, TF);
        for (int f = imin(excl, TF); f < e0; ++f) po16[f] = (short)(2 * tid);
        for (int f = e0; f < e1; ++f) po16[f] = (short)(2 * tid + 1);
        __syncthreads();

        float wA[16], wB[16], wC[16];
#pragma unroll
        for (int r = 0; r < 16; ++r) {
            wA[r] = pemb_w[c0 + r];
            wB[r] = pemb_b[c0 + r] + eemb_b[c0 + r];
            wC[r] = eemb_w[c0 + r];
        }
        const float* fm_b = frame_mask + (size_t)b * TF;
        const float* lc_b = log_cf0 + (size_t)b * TF;
        const float* en_b = energy + (size_t)b * TF;
        float* ob = out + ((size_t)b * CC + c0) * TF;
        int fbase = wv * 512;

#pragma unroll
        for (int it = 0; it < 2; ++it) {
            int f0 = fbase + it * 256 + lane;  // component k handles frame f0 + 64k
            int p[4], pcl[4];
            float fmv[4], lcv[4], env[4];
#pragma unroll
            for (int k = 0; k < 4; ++k) {
                int f = f0 + 64 * k;
                p[k] = po16[f];           // sign-extends; -1 = unmapped frame
                pcl[k] = imax(p[k], 0);
                fmv[k] = fm_b[f];
                lcv[k] = lc_b[f];
                env[k] = en_b[f];
            }
#pragma unroll
            for (int r = 0; r < 16; ++r) {
                const float* xsr = xs + r * TP;
                float* obr = ob + (size_t)r * TF + f0;
#pragma unroll
                for (int k = 0; k < 4; ++k) {
                    float xv = xsr[pcl[k]];               // <=2-way bank aliasing
                    float v = (p[k] >= 0) ? xv : 0.f;
                    float t = __builtin_fmaf(lcv[k], wA[r], wB[r]);
                    t = __builtin_fmaf(env[k], wC[r], t);
                    float o = (v + t) * fmv[k];
                    __builtin_nontemporal_store(o, obr + 64 * k);
                }
            }
        }
    } else {
        // ---------------- GEMV + preds block ----------------
        int jj = j - 24;  // 0..7, phones [jj*64, jj*64+64)
        __shared__ float r[16 * 64];
        __shared__ int ps[256];
        __shared__ float y_lds[3 * 64];
        __shared__ float pm_lds[64];
        __shared__ short po_win[192];
        int t = jj * 64 + lane;
        float a0 = 0.f, a1 = 0.f, a2 = 0.f, a3 = 0.f;
#pragma unroll 8
        for (int i = 0; i < CC / 4; ++i) {
            int c = __builtin_amdgcn_readfirstlane(wv + 4 * i);
            float xv = xb[c * TP + t];
            a0 += xv * pitch_w[c];
            a1 += xv * pitch_w[CC + c];
            a2 += xv * enp_w[c];
            a3 += xv * dur_w[c];
        }
        r[(0 * 4 + wv) * 64 + lane] = a0;
        r[(1 * 4 + wv) * 64 + lane] = a1;
        r[(2 * 4 + wv) * 64 + lane] = a2;
        r[(3 * 4 + wv) * 64 + lane] = a3;
        int2 d01 = *(const int2*)(duration + b * TP + 2 * tid);
        int d0 = d01.x, d1 = d01.y;
        ps[tid] = d0 + d1;
        if (tid < 64) pm_lds[tid] = phone_mask[b * TP + jj * 64 + tid];
        __syncthreads();
        for (int off = 1; off < 256; off <<= 1) {
            int v = (tid >= off) ? ps[tid - off] : 0;
            __syncthreads();
            ps[tid] += v;
            __syncthreads();
        }
        // y reduce: wave wv owns output o=wv
        float a = 0.f;
#pragma unroll
        for (int k = 0; k < 4; ++k) a += r[(wv * 4 + k) * 64 + lane];
        if (wv == 3)
            ldp[b * TP + t] = (a + dur_b[0]) * pm_lds[lane];
        else
            y_lds[wv * 64 + lane] = a;
        // window scatter by the 32 owning pair-threads
        int base_lo = (jj > 0) ? imin(ps[jj * 32 - 1], TF) : 0;
        int base_hi = imin(ps[(jj + 1) * 32 - 1], TF);
        if (tid >= jj * 32 && tid < (jj + 1) * 32) {
            int excl = tid ? ps[tid - 1] : 0;
            int e0 = imin(excl + d0, TF);
            int e1 = imin(excl + d0 + d1, TF);
            for (int f = imin(excl, TF); f < e0; ++f) po_win[f - base_lo] = (short)(2 * tid - jj * 64);
            for (int f = e0; f < e1; ++f) po_win[f - base_lo] = (short)(2 * tid + 1 - jj * 64);
        }
        int total = imin(ps[255], TF);
        __syncthreads();
        int win = base_hi - base_lo;
        for (int idx = tid; idx < win; idx += 256) {
            int f = base_lo + idx;
            int p = po_win[idx];
            float fm = frame_mask[b * TF + f];
            float xm = pm_lds[p] * fm;
            lcp[b * TF + f] = (y_lds[p] * xm + pitch_b[0]) * fm;
            vup[b * TF + f] = (y_lds[64 + p] * xm + pitch_b[1]) * fm;
            epp[b * TF + f] = (y_lds[128 + p] * xm + enp_b[0]) * fm;
        }
        if (jj == 7) {
            for (int f = total + tid; f < TF; f += 256) {
                float fm = frame_mask[b * TF + f];
                lcp[b * TF + f] = pitch_b[0] * fm;
                vup[b * TF + f] = pitch_b[1] * fm;
                epp[b * TF + f] = enp_b[0] * fm;
            }
        }
    }
}

extern "C" void kernel_launch(void* const* d_in, const int* in_sizes, int n_in,
                              void* d_out, int out_size, void* d_ws, size_t ws_size,
                              hipStream_t stream) {
    const float* x          = (const float*)d_in[0];
    const float* phone_mask = (const float*)d_in[1];
    const float* frame_mask = (const float*)d_in[2];
    const int*   duration   = (const int*)d_in[3];
    const float* log_cf0    = (const float*)d_in[4];
    const float* energy     = (const float*)d_in[6];
    const float* dur_w      = (const float*)d_in[7];
    const float* dur_b      = (const float*)d_in[8];
    const float* pitch_w    = (const float*)d_in[9];
    const float* pitch_b    = (const float*)d_in[10];
    const float* pemb_w     = (const float*)d_in[11];
    const float* pemb_b     = (const float*)d_in[12];
    const float* enp_w      = (const float*)d_in[13];
    const float* enp_b      = (const float*)d_in[14];
    const float* eemb_w     = (const float*)d_in[15];
    const float* eemb_b     = (const float*)d_in[16];

    float* out = (float*)d_out;
    float* ldp = out + (size_t)BB * CC * TF;
    float* lcp = ldp + (size_t)BB * TP;
    float* vup = lcp + (size_t)BB * TF;
    float* epp = vup + (size_t)BB * TF;

    mono_kernel<<<dim3(32, BB), dim3(256), 0, stream>>>(
        x, phone_mask, frame_mask, duration, log_cf0, energy, dur_w, dur_b,
        pitch_w, pitch_b, pemb_w, pemb_b, enp_w, enp_b, eemb_w, eemb_b,
        out, ldp, lcp, vup, epp);
}